// Round 14
// baseline (166.950 us; speedup 1.0000x reference)
//
#include <hip/hip_runtime.h>
#include <cstdint>
#include <cstddef>

// ---------------- types ----------------
typedef _Float16 h8 __attribute__((ext_vector_type(8)));
typedef _Float16 h4 __attribute__((ext_vector_type(4)));
typedef __fp16   g2 __attribute__((ext_vector_type(2)));   // cvt_pkrtz result type
typedef float    f32x4 __attribute__((ext_vector_type(4)));

constexpr int B_ = 8, N_ = 1024, E_ = 512, H_ = 8, D_ = 64, F_ = 2048;
constexpr int M_ = B_ * N_;   // 8192 rows
constexpr int HD_ = H_ * D_;  // 512

// q pre-scale: 1/sqrt(D) * log2(e)  (softmax done in base 2)
#define QSCALE2 0.18033688011112042f

#define GLOAD_LDS16(gp, lp)                                                        \
    __builtin_amdgcn_global_load_lds((const __attribute__((address_space(1))) void*)(gp), \
                                     (__attribute__((address_space(3))) void*)(lp), 16, 0, 0)

// raw hardware exp2 (no libm denormal guard; underflow -> 0 is fine for softmax)
__device__ __forceinline__ float exp2_raw(float x) {
#if __has_builtin(__builtin_amdgcn_exp2f)
    return __builtin_amdgcn_exp2f(x);
#else
    float r;
    asm("v_exp_f32 %0, %1\n\ts_nop 0" : "=v"(r) : "v"(x));
    return r;
#endif
}

// ---------------- fused prep: weight transposes (z<12) + x f32->f16 (z==12) ----
__global__ void __launch_bounds__(256) k_pre(
    const float* __restrict__ x, _Float16* __restrict__ xh,
    const float* __restrict__ Wq, const float* __restrict__ Wk,
    const float* __restrict__ Wv, const float* __restrict__ Wo,
    const float* __restrict__ W1, const float* __restrict__ W2,
    _Float16* __restrict__ oqkv, _Float16* __restrict__ oo,
    _Float16* __restrict__ o1, _Float16* __restrict__ o2) {
    if (blockIdx.z == 12) {
        int i = (blockIdx.x * 256 + threadIdx.x) * 16;
#pragma unroll
        for (int j = 0; j < 4; ++j) {
            float4 v = *(const float4*)(x + i + j * 4);
            h4 o = {(_Float16)v.x, (_Float16)v.y, (_Float16)v.z, (_Float16)v.w};
            *(h4*)(xh + i + j * 4) = o;
        }
        return;
    }
    if (blockIdx.x >= 256) return;
    const float* in;
    _Float16* out;
    int R, C, gt = blockIdx.x;
    switch (blockIdx.z) {
        case 0: in = Wq; out = oqkv;              R = 512;  C = 512;  break;
        case 1: in = Wk; out = oqkv + 512 * 512;  R = 512;  C = 512;  break;
        case 2: in = Wv; out = oqkv + 1024 * 512; R = 512;  C = 512;  break;
        case 3: in = Wo; out = oo;                R = 512;  C = 512;  break;
        default:
            if (blockIdx.z < 8) { in = W1; out = o1; R = 512;  C = 2048; gt += (blockIdx.z - 4) * 256; }
            else                { in = W2; out = o2; R = 2048; C = 512;  gt += (blockIdx.z - 8) * 256; }
    }
    const int ctiles = C >> 5;
    const int ty = gt / ctiles, tx = gt - ty * ctiles;
    const int r0 = ty * 32, c0 = tx * 32;
    __shared__ float lt[32][33];
    const int rr = threadIdx.x >> 3, cq = threadIdx.x & 7;
    float4 v = *(const float4*)&in[(size_t)(r0 + rr) * C + c0 + cq * 4];
    lt[rr][cq * 4 + 0] = v.x; lt[rr][cq * 4 + 1] = v.y;
    lt[rr][cq * 4 + 2] = v.z; lt[rr][cq * 4 + 3] = v.w;
    __syncthreads();
    h4 o = {(_Float16)lt[cq * 4 + 0][rr], (_Float16)lt[cq * 4 + 1][rr],
            (_Float16)lt[cq * 4 + 2][rr], (_Float16)lt[cq * 4 + 3][rr]};
    *(h4*)&out[(size_t)(c0 + rr) * R + r0 + cq * 4] = o;
}

// ---------------- GEMM: C = A[M][K] * Bt[N][K]^T, f16 in, fp32 acc ----------------
// BM=64, BN templated, 4 waves in 2x2, wave tile 32 x (BN/2). T1 XCD decode,
// T2 XOR-swizzle, and NEW: T4 counted-vmcnt 3-buffer pipeline — prologue stages
// tiles 0,1; each iter waits vmcnt(L) (only tile t's loads; tile t+1 stays in
// flight across the barrier), raw s_barrier, then stages tile t+2 into the
// buffer freed at the previous barrier. Last iter peeled with vmcnt(0).
// EPI 0: QKV scatter (q *= QSCALE2, k direct, v transposed via LDS)
// EPI 2: outh = relu(acc + bias[col])                      (f16)
// EPI 3: outh = f16(acc + bias[col] + resh_f16[row][col])  (residual add)
template <int BN, int EPI>
__global__ void __launch_bounds__(256) k_gemm(
    const _Float16* __restrict__ A, const _Float16* __restrict__ Bt,
    int Mg, int Ng, int Kg,
    const float* __restrict__ bias,
    const _Float16* __restrict__ resh, _Float16* __restrict__ outh,
    _Float16* __restrict__ qp, _Float16* __restrict__ kp, _Float16* __restrict__ vtp) {
    constexpr int WN = BN / 2;       // wave tile cols
    constexpr int NI = WN / 16;      // n-frags per wave
    __shared__ alignas(16) _Float16 lA[3][64 * 64];
    __shared__ alignas(16) _Float16 lB[3][BN * 64];

    const int tid = threadIdx.x;
    const int lane = tid & 63;
    const int wid = tid >> 6;
    const int wr = wid >> 1, wc = wid & 1;
    const int r16 = lane & 15, hseg = lane >> 4;

    // XCD-aware tile decode (M tiles = 128: 16 per XCD)
    const int bid = blockIdx.x;
    const int xcd = bid & 7;
    const int rem = bid >> 3;
    const int tx = rem >> 4, tyl = rem & 15;
    const int m0 = (xcd * 16 + tyl) * 64;
    const int n0 = tx * BN;

    auto STAGE = [&](int buf, int k0) {
#pragma unroll
        for (int i = 0; i < 2; ++i) {
            const int slot = i * 256 + tid, row = slot >> 3;
            const int cs = (slot & 7) ^ (row & 7);
            GLOAD_LDS16(A + (size_t)(m0 + row) * Kg + k0 + cs * 8, &lA[buf][slot * 8]);
        }
#pragma unroll
        for (int i = 0; i < BN / 32; ++i) {
            const int slot = i * 256 + tid, row = slot >> 3;
            const int cs = (slot & 7) ^ (row & 7);
            GLOAD_LDS16(Bt + (size_t)(n0 + row) * Kg + k0 + cs * 8, &lB[buf][slot * 8]);
        }
    };

    f32x4 acc[2][NI] = {};
    const int nt = Kg >> 6;   // 8 or 32, always >= 2

    auto COMPUTE = [&](const int buf) __attribute__((always_inline)) {
#pragma unroll
        for (int kk = 0; kk < 2; ++kk) {
            h8 af[2], bf[NI];
#pragma unroll
            for (int mi = 0; mi < 2; ++mi) {
                const int row = wr * 32 + mi * 16 + r16;
                af[mi] = *(const h8*)&lA[buf][row * 64 + (((kk * 4 + hseg) ^ (row & 7)) * 8)];
            }
#pragma unroll
            for (int ni = 0; ni < NI; ++ni) {
                const int row = wc * WN + ni * 16 + r16;
                bf[ni] = *(const h8*)&lB[buf][row * 64 + (((kk * 4 + hseg) ^ (row & 7)) * 8)];
            }
#pragma unroll
            for (int mi = 0; mi < 2; ++mi)
#pragma unroll
                for (int ni = 0; ni < NI; ++ni)
                    acc[mi][ni] =
                        __builtin_amdgcn_mfma_f32_16x16x32_f16(af[mi], bf[ni], acc[mi][ni], 0, 0, 0);
        }
    };

    STAGE(0, 0);
    STAGE(1, 64);
    for (int t = 0; t < nt - 1; ++t) {
        // wait only for tile t's loads (tile t+1's stay in flight: counted, not 0)
        if constexpr (BN == 128) asm volatile("s_waitcnt vmcnt(6)" ::: "memory");
        else                     asm volatile("s_waitcnt vmcnt(4)" ::: "memory");
        __builtin_amdgcn_sched_barrier(0);
        __builtin_amdgcn_s_barrier();       // all waves' tile-t LDS writes landed
        __builtin_amdgcn_sched_barrier(0);
        if (t + 2 < nt) STAGE((t + 2) % 3, (t + 2) << 6);  // buffer freed at prev barrier
        COMPUTE(t % 3);
    }
    asm volatile("s_waitcnt vmcnt(0)" ::: "memory");
    __builtin_amdgcn_sched_barrier(0);
    __builtin_amdgcn_s_barrier();
    __builtin_amdgcn_sched_barrier(0);
    COMPUTE((nt - 1) % 3);

    // epilogue: lane holds C[row = m0+wr*32+mi*16+hseg*4+r][col = n0+wc*WN+ni*16+r16]
    if constexpr (EPI == 0) {
        if (n0 >= 1024) {
            __syncthreads();  // all waves done reading lA before reuse as scratch
            // V block: transpose 64xBN C-tile through LDS, coalesced h8 stores.
            _Float16* lC = &lA[0][0];
#pragma unroll
            for (int mi = 0; mi < 2; ++mi) {
                const int r0 = wr * 32 + mi * 16 + hseg * 4;
                const int s = r0 >> 3, ro = r0 & 7;
#pragma unroll
                for (int ni = 0; ni < NI; ++ni) {
                    const int c = wc * WN + ni * 16 + r16;
                    h4 pv = {(_Float16)acc[mi][ni][0], (_Float16)acc[mi][ni][1],
                             (_Float16)acc[mi][ni][2], (_Float16)acc[mi][ni][3]};
                    *(h4*)&lC[c * 64 + ((s ^ (c & 7)) << 3) + ro] = pv;
                }
            }
            __syncthreads();
            const int c = tid >> 1, half = tid & 1;
            const int b = m0 >> 10, nn0 = m0 & 1023;
            _Float16* gdst =
                vtp + ((size_t)(b * 512 + (n0 - 1024) + c)) * 1024 + nn0 + half * 32;
#pragma unroll
            for (int j = 0; j < 4; ++j) {
                const int s = half * 4 + j;
                h8 v = *(const h8*)&lC[c * 64 + ((s ^ (c & 7)) << 3)];
                *(h8*)&gdst[j * 8] = v;
            }
        } else {
#pragma unroll
            for (int mi = 0; mi < 2; ++mi)
#pragma unroll
                for (int ni = 0; ni < NI; ++ni)
#pragma unroll
                    for (int r = 0; r < 4; ++r) {
                        int row = m0 + wr * 32 + mi * 16 + hseg * 4 + r;
                        int col = n0 + wc * WN + ni * 16 + r16;
                        float v = acc[mi][ni][r];
                        int cc = col & 511;
                        int h = cc >> 6, d = cc & 63;
                        int b = row >> 10, nn = row & 1023;
                        if (col < 512)
                            qp[((b * 8 + h) * 1024 + nn) * 64 + d] = (_Float16)(v * QSCALE2);
                        else
                            kp[((b * 8 + h) * 1024 + nn) * 64 + d] = (_Float16)v;
                    }
        }
    } else {
#pragma unroll
        for (int mi = 0; mi < 2; ++mi)
#pragma unroll
            for (int ni = 0; ni < NI; ++ni)
#pragma unroll
                for (int r = 0; r < 4; ++r) {
                    int row = m0 + wr * 32 + mi * 16 + hseg * 4 + r;
                    int col = n0 + wc * WN + ni * 16 + r16;
                    float v = acc[mi][ni][r] + bias[col];
                    if constexpr (EPI == 3) {
                        v += (float)resh[(size_t)row * Ng + col];
                    } else {
                        v = v > 0.f ? v : 0.f;
                    }
                    outh[(size_t)row * Ng + col] = (_Float16)v;
                }
    }
}

// ---------------- flash attention: 1 block = (b,h) x 128 q-rows, 8 waves --------
// R10/R12 2-buffer structure (4-buffer was null): swapped QK^T, XOR-swizzle,
// per-lane partial softmax sum, rare defer-max rescale, setprio on MFMA clusters.
__global__ void __launch_bounds__(512) k_attn(const _Float16* __restrict__ q,
                                              const _Float16* __restrict__ k,
                                              const _Float16* __restrict__ vt,
                                              _Float16* __restrict__ attn) {
    __shared__ alignas(16) _Float16 lK[2][64 * 64];   // [key][d], swizzled
    __shared__ alignas(16) _Float16 lV[2][64 * 64];   // [d][key], swizzled
    __shared__ alignas(16) _Float16 lP[8][16 * 64];   // per-wave P tile, swizzled

    const int tid = threadIdx.x, lane = tid & 63, w = tid >> 6;
    const int bid = blockIdx.x;                  // 512 blocks = 64 per XCD
    const int xcd = bid & 7, rem = bid >> 3;
    const int bh = xcd * 8 + (rem & 7);
    const int q0 = (rem >> 3) * 128;
    const int r16 = lane & 15, hseg = lane >> 4;
    const size_t base = (size_t)bh * N_ * D_;

    h8 qf0 = *(const h8*)&q[base + (size_t)(q0 + w * 16 + r16) * 64 + hseg * 8];
    h8 qf1 = *(const h8*)&q[base + (size_t)(q0 + w * 16 + r16) * 64 + 32 + hseg * 8];

    const int srow = tid >> 3;
    const int scsrc = (tid & 7) ^ (srow & 7);

    auto STAGE = [&](int buf, int kt) {
        GLOAD_LDS16(k + base + kt * 4096 + srow * 64 + scsrc * 8, &lK[buf][tid * 8]);
        GLOAD_LDS16(vt + base + (size_t)srow * N_ + kt * 64 + scsrc * 8, &lV[buf][tid * 8]);
    };

    float mrun = -1e30f, lrun = 0.f;
    f32x4 oacc[4] = {};  // O[q = hseg*4+r][d = nf*16+r16]

    const char* lKb = (const char*)&lK[0][0];
    const char* lVb = (const char*)&lV[0][0];
    char* lPb = (char*)&lP[0][0] + w * 2048;
    const int swz = r16 & 7;
    const int kb0 = r16 * 128 + ((hseg ^ swz) * 16);        // kc=0 (lK & lV share)
    const int kb1 = r16 * 128 + (((4 + hseg) ^ swz) * 16);  // kc=1
    const int pswz = swz * 8;
    const int prd0 = r16 * 128 + (((hseg * 8) ^ pswz) * 2);
    const int prd1 = r16 * 128 + (((32 + hseg * 8) ^ pswz) * 2);
    const int pwr0 = r16 * 128 + (((0 + hseg * 4) ^ pswz) * 2);
    const int pwr1 = r16 * 128 + (((16 + hseg * 4) ^ pswz) * 2);
    const int pwr2 = r16 * 128 + (((32 + hseg * 4) ^ pswz) * 2);
    const int pwr3 = r16 * 128 + (((48 + hseg * 4) ^ pswz) * 2);

    auto TILE = [&](const int cur, const int kt) __attribute__((always_inline)) {
        if (kt + 1 < N_ / 64) STAGE(cur ^ 1, kt + 1);  // prefetch overlaps compute
        const int cOff = cur * 8192;  // one buffer = 64*64*2 bytes

        float sv[4][4];
        __builtin_amdgcn_s_setprio(1);
#pragma unroll
        for (int t4 = 0; t4 < 4; ++t4) {
            f32x4 a = {};
            h8 kf0 = *(const h8*)(lKb + cOff + t4 * 2048 + kb0);
            a = __builtin_amdgcn_mfma_f32_16x16x32_f16(kf0, qf0, a, 0, 0, 0);
            h8 kf1 = *(const h8*)(lKb + cOff + t4 * 2048 + kb1);
            a = __builtin_amdgcn_mfma_f32_16x16x32_f16(kf1, qf1, a, 0, 0, 0);
#pragma unroll
            for (int r = 0; r < 4; ++r) sv[t4][r] = a[r];
        }
        __builtin_amdgcn_s_setprio(0);

        float m0a = fmaxf(fmaxf(sv[0][0], sv[0][1]), fmaxf(sv[0][2], sv[0][3]));
        float m1a = fmaxf(fmaxf(sv[1][0], sv[1][1]), fmaxf(sv[1][2], sv[1][3]));
        float m2a = fmaxf(fmaxf(sv[2][0], sv[2][1]), fmaxf(sv[2][2], sv[2][3]));
        float m3a = fmaxf(fmaxf(sv[3][0], sv[3][1]), fmaxf(sv[3][2], sv[3][3]));
        float mx = fmaxf(fmaxf(m0a, m1a), fmaxf(m2a, m3a));

        if (__any(mx > mrun + 8.f)) {
            mx = fmaxf(mx, __shfl_xor(mx, 16));
            mx = fmaxf(mx, __shfl_xor(mx, 32));
            float mnew = fmaxf(mrun, mx);
            float sc = exp2_raw(mrun - mnew);
            mrun = mnew;
            lrun *= sc;
#pragma unroll
            for (int r = 0; r < 4; ++r) {
                float scq = __shfl(sc, hseg * 4 + r);
#pragma unroll
                for (int nf = 0; nf < 4; ++nf) oacc[nf][r] *= scq;
            }
        }

        float p[4][4];
        float rsum = 0.f;
#pragma unroll
        for (int t4 = 0; t4 < 4; ++t4)
#pragma unroll
            for (int r = 0; r < 4; ++r) {
                p[t4][r] = exp2_raw(sv[t4][r] - mrun);
                rsum += p[t4][r];
            }
        lrun += rsum;

#pragma unroll
        for (int t4 = 0; t4 < 4; ++t4) {
            g2 a0 = __builtin_amdgcn_cvt_pkrtz(p[t4][0], p[t4][1]);
            g2 a1 = __builtin_amdgcn_cvt_pkrtz(p[t4][2], p[t4][3]);
            h4 pv = {(_Float16)a0[0], (_Float16)a0[1], (_Float16)a1[0], (_Float16)a1[1]};
            char* dst = lPb + (t4 == 0 ? pwr0 : t4 == 1 ? pwr1 : t4 == 2 ? pwr2 : pwr3);
            *(h4*)dst = pv;
        }
        asm volatile("s_waitcnt lgkmcnt(0)" ::: "memory");  // wave-internal LDS fence

        h8 pa0 = *(const h8*)(lPb + prd0);
        h8 pa1 = *(const h8*)(lPb + prd1);
        __builtin_amdgcn_s_setprio(1);
#pragma unroll
        for (int nf = 0; nf < 4; ++nf) {
            h8 vb0 = *(const h8*)(lVb + cOff + nf * 2048 + kb0);
            oacc[nf] = __builtin_amdgcn_mfma_f32_16x16x32_f16(pa0, vb0, oacc[nf], 0, 0, 0);
            h8 vb1 = *(const h8*)(lVb + cOff + nf * 2048 + kb1);
            oacc[nf] = __builtin_amdgcn_mfma_f32_16x16x32_f16(pa1, vb1, oacc[nf], 0, 0, 0);
        }
        __builtin_amdgcn_s_setprio(0);
        __syncthreads();  // drains prefetch vmcnt + guards buffer swap
    };

    STAGE(0, 0);
    __syncthreads();  // drains vmcnt: buf0 ready

    for (int kt = 0; kt < N_ / 64; kt += 2) {
        TILE(0, kt);
        TILE(1, kt + 1);
    }

    lrun += __shfl_xor(lrun, 16);
    lrun += __shfl_xor(lrun, 32);

    float rlin = 1.f / lrun;
    int b = bh >> 3, h = bh & 7;
#pragma unroll
    for (int r = 0; r < 4; ++r) {
        float inv = __shfl(rlin, hseg * 4 + r);
        int row = b * 1024 + q0 + w * 16 + hseg * 4 + r;
#pragma unroll
        for (int nf = 0; nf < 4; ++nf) {
            int col = h * 64 + nf * 16 + r16;
            attn[(size_t)row * 512 + col] = (_Float16)(oacc[nf][r] * inv);
        }
    }
}

// ---------------- layernorm: 1 wave per row of 512, f16 in ----------------
// OUTF32=1: write f32 (+tail); else write f16.
template <int OUTF32>
__global__ void __launch_bounds__(256) k_ln(const _Float16* __restrict__ x,
                                            const float* __restrict__ g,
                                            const float* __restrict__ b,
                                            float* __restrict__ outf,
                                            _Float16* __restrict__ outh,
                                            float* __restrict__ tail) {
    int row = blockIdx.x * 4 + (threadIdx.x >> 6);
    int lane = threadIdx.x & 63;
    h8 v = *(const h8*)(x + (size_t)row * 512 + lane * 8);
    float f[8];
    float s = 0.f, sq = 0.f;
#pragma unroll
    for (int j = 0; j < 8; ++j) {
        f[j] = (float)v[j];
        s += f[j];
        sq += f[j] * f[j];
    }
#pragma unroll
    for (int msk = 1; msk < 64; msk <<= 1) {
        s += __shfl_xor(s, msk);
        sq += __shfl_xor(sq, msk);
    }
    float mu = s * (1.f / 512.f);
    float var = sq * (1.f / 512.f) - mu * mu;
    float rstd = rsqrtf(var + 1e-5f);
    float4 ga = *(const float4*)(g + lane * 8);
    float4 gb = *(const float4*)(g + lane * 8 + 4);
    float4 ba = *(const float4*)(b + lane * 8);
    float4 bb = *(const float4*)(b + lane * 8 + 4);
    float o[8];
    o[0] = (f[0] - mu) * rstd * ga.x + ba.x;
    o[1] = (f[1] - mu) * rstd * ga.y + ba.y;
    o[2] = (f[2] - mu) * rstd * ga.z + ba.z;
    o[3] = (f[3] - mu) * rstd * ga.w + ba.w;
    o[4] = (f[4] - mu) * rstd * gb.x + bb.x;
    o[5] = (f[5] - mu) * rstd * gb.y + bb.y;
    o[6] = (f[6] - mu) * rstd * gb.z + bb.z;
    o[7] = (f[7] - mu) * rstd * gb.w + bb.w;
    if constexpr (OUTF32) {
        float* orow = outf + (size_t)row * 512 + lane * 8;
        *(float4*)(orow) = make_float4(o[0], o[1], o[2], o[3]);
        *(float4*)(orow + 4) = make_float4(o[4], o[5], o[6], o[7]);
        if (tail && blockIdx.x == 0 && threadIdx.x == 0) tail[0] = 0.f;
    } else {
        h8 oh = {(_Float16)o[0], (_Float16)o[1], (_Float16)o[2], (_Float16)o[3],
                 (_Float16)o[4], (_Float16)o[5], (_Float16)o[6], (_Float16)o[7]};
        *(h8*)(outh + (size_t)row * 512 + lane * 8) = oh;
    }
}

// ---------------- launch ----------------
extern "C" void kernel_launch(void* const* d_in, const int* in_sizes, int n_in,
                              void* d_out, int out_size, void* d_ws, size_t ws_size,
                              hipStream_t stream) {
    const float* x   = (const float*)d_in[0];
    const float* Wq  = (const float*)d_in[1];
    const float* Wk  = (const float*)d_in[2];
    const float* Wv  = (const float*)d_in[3];
    const float* Wo  = (const float*)d_in[4];
    const float* bo  = (const float*)d_in[5];
    const float* g1  = (const float*)d_in[6];
    const float* b1  = (const float*)d_in[7];
    const float* W1  = (const float*)d_in[8];
    const float* bf1 = (const float*)d_in[9];
    const float* W2  = (const float*)d_in[10];
    const float* bf2 = (const float*)d_in[11];
    const float* g2  = (const float*)d_in[12];
    const float* b2  = (const float*)d_in[13];
    float* out = (float*)d_out;

    char* ws = (char*)d_ws;
    _Float16* xh    = (_Float16*)(ws + 0);            // 8 MB; reused as out1h after Wo
    _Float16* wqkvT = (_Float16*)(ws + 8388608);      // 1.5 MB  [1536][512]
    _Float16* woT   = (_Float16*)(ws + 9961472);      // 0.5 MB
    _Float16* w1T   = (_Float16*)(ws + 10485760);     // 2 MB    [2048][512]
    _Float16* w2T   = (_Float16*)(ws + 12582912);     // 2 MB    [512][2048]
    _Float16* qb    = (_Float16*)(ws + 14680064);     // 8 MB; ff (32 MB) reuses qb..attnb
    _Float16* kb    = (_Float16*)(ws + 23068672);     // 8 MB
    _Float16* vtb   = (_Float16*)(ws + 31457280);     // 8 MB
    _Float16* attnb = (_Float16*)(ws + 39845888);     // 8 MB
    _Float16* h1h   = (_Float16*)(ws + 48234496);     // 8 MB f16 (h1, reused as h2)
    _Float16* out1h = xh;
    _Float16* ff    = qb;

    // stage 0: fused dtype conversion + weight transposes
    k_pre<<<dim3(1024, 1, 13), 256, 0, stream>>>(x, xh, Wq, Wk, Wv, Wo, W1, W2,
                                                 wqkvT, woT, w1T, w2T);

    // QKV projection (fused, N=1536): BM=64/BN=128 -> grid 12*128 = 1536
    k_gemm<128, 0><<<dim3(1536), 256, 0, stream>>>(
        xh, wqkvT, M_, 1536, 512, nullptr, nullptr, nullptr, qb, kb, vtb);

    // attention: 512 blocks x 8 waves, XCD-decoded
    k_attn<<<dim3(512), 512, 0, stream>>>(qb, kb, vtb, attnb);

    // Wo projection + bias + residual(xh, f16) -> h1h: BM=64/BN=64 -> grid 1024
    k_gemm<64, 3><<<dim3(1024), 256, 0, stream>>>(
        attnb, woT, M_, 512, 512, bo, xh, h1h, nullptr, nullptr, nullptr);

    // LN1 -> out1h (f16; overwrites xh AFTER Wo consumed it)
    k_ln<0><<<dim3(M_ / 4), 256, 0, stream>>>(h1h, g1, b1, nullptr, out1h, nullptr);

    // FFN1: relu(out1 @ W1 + bf1) -> ff (f16): BM=64/BN=128 -> grid 2048
    k_gemm<128, 2><<<dim3(2048), 256, 0, stream>>>(
        out1h, w1T, M_, 2048, 512, bf1, nullptr, ff, nullptr, nullptr, nullptr);

    // FFN2: ff @ W2 + bf2 + out1 (f16 residual) -> h1h reused: BM=64/BN=64 -> 1024
    k_gemm<64, 3><<<dim3(1024), 256, 0, stream>>>(
        ff, w2T, M_, 512, 2048, bf2, out1h, h1h, nullptr, nullptr, nullptr);

    // LN2 -> d_out (fp32) + trailing scalar (reference returns (out3, 0))
    k_ln<1><<<dim3(M_ / 4), 256, 0, stream>>>(h1h, g2, b2, out, nullptr, out + (size_t)M_ * E_);
}

// Round 15
// 144.588 us; speedup vs baseline: 1.1547x; 1.1547x over previous
//
#include <hip/hip_runtime.h>
#include <cstdint>
#include <cstddef>

// ---------------- types ----------------
typedef _Float16 h8 __attribute__((ext_vector_type(8)));
typedef _Float16 h4 __attribute__((ext_vector_type(4)));
typedef __fp16   g2 __attribute__((ext_vector_type(2)));   // cvt_pkrtz result type
typedef float    f32x4 __attribute__((ext_vector_type(4)));

constexpr int B_ = 8, N_ = 1024, E_ = 512, H_ = 8, D_ = 64, F_ = 2048;
constexpr int M_ = B_ * N_;   // 8192 rows
constexpr int HD_ = H_ * D_;  // 512

// q pre-scale: 1/sqrt(D) * log2(e)  (softmax done in base 2)
#define QSCALE2 0.18033688011112042f

#define GLOAD_LDS16(gp, lp)                                                        \
    __builtin_amdgcn_global_load_lds((const __attribute__((address_space(1))) void*)(gp), \
                                     (__attribute__((address_space(3))) void*)(lp), 16, 0, 0)

// raw hardware exp2 (no libm denormal guard; underflow -> 0 is fine for softmax)
__device__ __forceinline__ float exp2_raw(float x) {
#if __has_builtin(__builtin_amdgcn_exp2f)
    return __builtin_amdgcn_exp2f(x);
#else
    float r;
    asm("v_exp_f32 %0, %1\n\ts_nop 0" : "=v"(r) : "v"(x));
    return r;
#endif
}

// ---------------- fused prep: weight transposes (z<12) + x f32->f16 (z==12) ----
__global__ void __launch_bounds__(256) k_pre(
    const float* __restrict__ x, _Float16* __restrict__ xh,
    const float* __restrict__ Wq, const float* __restrict__ Wk,
    const float* __restrict__ Wv, const float* __restrict__ Wo,
    const float* __restrict__ W1, const float* __restrict__ W2,
    _Float16* __restrict__ oqkv, _Float16* __restrict__ oo,
    _Float16* __restrict__ o1, _Float16* __restrict__ o2) {
    if (blockIdx.z == 12) {
        int i = (blockIdx.x * 256 + threadIdx.x) * 16;
#pragma unroll
        for (int j = 0; j < 4; ++j) {
            float4 v = *(const float4*)(x + i + j * 4);
            h4 o = {(_Float16)v.x, (_Float16)v.y, (_Float16)v.z, (_Float16)v.w};
            *(h4*)(xh + i + j * 4) = o;
        }
        return;
    }
    if (blockIdx.x >= 256) return;
    const float* in;
    _Float16* out;
    int R, C, gt = blockIdx.x;
    switch (blockIdx.z) {
        case 0: in = Wq; out = oqkv;              R = 512;  C = 512;  break;
        case 1: in = Wk; out = oqkv + 512 * 512;  R = 512;  C = 512;  break;
        case 2: in = Wv; out = oqkv + 1024 * 512; R = 512;  C = 512;  break;
        case 3: in = Wo; out = oo;                R = 512;  C = 512;  break;
        default:
            if (blockIdx.z < 8) { in = W1; out = o1; R = 512;  C = 2048; gt += (blockIdx.z - 4) * 256; }
            else                { in = W2; out = o2; R = 2048; C = 512;  gt += (blockIdx.z - 8) * 256; }
    }
    const int ctiles = C >> 5;
    const int ty = gt / ctiles, tx = gt - ty * ctiles;
    const int r0 = ty * 32, c0 = tx * 32;
    __shared__ float lt[32][33];
    const int rr = threadIdx.x >> 3, cq = threadIdx.x & 7;
    float4 v = *(const float4*)&in[(size_t)(r0 + rr) * C + c0 + cq * 4];
    lt[rr][cq * 4 + 0] = v.x; lt[rr][cq * 4 + 1] = v.y;
    lt[rr][cq * 4 + 2] = v.z; lt[rr][cq * 4 + 3] = v.w;
    __syncthreads();
    h4 o = {(_Float16)lt[cq * 4 + 0][rr], (_Float16)lt[cq * 4 + 1][rr],
            (_Float16)lt[cq * 4 + 2][rr], (_Float16)lt[cq * 4 + 3][rr]};
    *(h4*)&out[(size_t)(c0 + rr) * R + r0 + cq * 4] = o;
}

// ---------------- GEMM (R12-verified): BM=64, BN=128, 256 threads ----------------
// 4 waves 2x2, wave tile 32x64. T1 XCD decode, T2 XOR-swizzle, 2-phase prefetch.
// EPI 0: QKV scatter (q *= QSCALE2, k direct, v transposed via LDS)
// EPI 2: outh = relu(acc + bias[col])  (f16)
template <int EPI>
__global__ void __launch_bounds__(256) k_gemm(
    const _Float16* __restrict__ A, const _Float16* __restrict__ Bt,
    int Mg, int Ng, int Kg,
    const float* __restrict__ bias,
    _Float16* __restrict__ outh,
    _Float16* __restrict__ qp, _Float16* __restrict__ kp, _Float16* __restrict__ vtp) {
    constexpr int BN = 128;
    constexpr int WN = BN / 2;       // wave tile cols
    constexpr int NI = WN / 16;      // n-frags per wave
    __shared__ alignas(16) _Float16 lA[2][64 * 64];
    __shared__ alignas(16) _Float16 lB[2][BN * 64];

    const int tid = threadIdx.x;
    const int lane = tid & 63;
    const int wid = tid >> 6;
    const int wr = wid >> 1, wc = wid & 1;
    const int r16 = lane & 15, hseg = lane >> 4;

    // XCD-aware tile decode (M tiles = 128: 16 per XCD)
    const int bid = blockIdx.x;
    const int xcd = bid & 7;
    const int rem = bid >> 3;
    const int tx = rem >> 4, tyl = rem & 15;
    const int m0 = (xcd * 16 + tyl) * 64;
    const int n0 = tx * BN;

    auto STAGE = [&](int buf, int k0) {
#pragma unroll
        for (int i = 0; i < 2; ++i) {
            const int slot = i * 256 + tid, row = slot >> 3;
            const int cs = (slot & 7) ^ (row & 7);
            GLOAD_LDS16(A + (size_t)(m0 + row) * Kg + k0 + cs * 8, &lA[buf][slot * 8]);
        }
#pragma unroll
        for (int i = 0; i < BN / 32; ++i) {
            const int slot = i * 256 + tid, row = slot >> 3;
            const int cs = (slot & 7) ^ (row & 7);
            GLOAD_LDS16(Bt + (size_t)(n0 + row) * Kg + k0 + cs * 8, &lB[buf][slot * 8]);
        }
    };

    f32x4 acc[2][NI] = {};
    const int nt = Kg >> 6;

    STAGE(0, 0);
    __syncthreads();  // vmcnt(0)+barrier: buf0 ready

    for (int t = 0; t < nt; ++t) {
        const int cur = t & 1;
        if (t + 1 < nt) STAGE(cur ^ 1, (t + 1) << 6);  // prefetch overlaps compute

#pragma unroll
        for (int kk = 0; kk < 2; ++kk) {
            h8 af[2], bf[NI];
#pragma unroll
            for (int mi = 0; mi < 2; ++mi) {
                const int row = wr * 32 + mi * 16 + r16;
                af[mi] = *(const h8*)&lA[cur][row * 64 + (((kk * 4 + hseg) ^ (row & 7)) * 8)];
            }
#pragma unroll
            for (int ni = 0; ni < NI; ++ni) {
                const int row = wc * WN + ni * 16 + r16;
                bf[ni] = *(const h8*)&lB[cur][row * 64 + (((kk * 4 + hseg) ^ (row & 7)) * 8)];
            }
#pragma unroll
            for (int mi = 0; mi < 2; ++mi)
#pragma unroll
                for (int ni = 0; ni < NI; ++ni)
                    acc[mi][ni] =
                        __builtin_amdgcn_mfma_f32_16x16x32_f16(af[mi], bf[ni], acc[mi][ni], 0, 0, 0);
        }
        __syncthreads();  // drains prefetch vmcnt + read lgkmcnt, guards buffer swap
    }

    // epilogue: lane holds C[row = m0+wr*32+mi*16+hseg*4+r][col = n0+wc*WN+ni*16+r16]
    if constexpr (EPI == 0) {
        if (n0 >= 1024) {
            // V block: transpose 64xBN C-tile through LDS, coalesced h8 stores.
            _Float16* lC = &lA[0][0];
#pragma unroll
            for (int mi = 0; mi < 2; ++mi) {
                const int r0 = wr * 32 + mi * 16 + hseg * 4;
                const int s = r0 >> 3, ro = r0 & 7;
#pragma unroll
                for (int ni = 0; ni < NI; ++ni) {
                    const int c = wc * WN + ni * 16 + r16;
                    h4 pv = {(_Float16)acc[mi][ni][0], (_Float16)acc[mi][ni][1],
                             (_Float16)acc[mi][ni][2], (_Float16)acc[mi][ni][3]};
                    *(h4*)&lC[c * 64 + ((s ^ (c & 7)) << 3) + ro] = pv;
                }
            }
            __syncthreads();
            const int c = tid >> 1, half = tid & 1;
            const int b = m0 >> 10, nn0 = m0 & 1023;
            _Float16* gdst =
                vtp + ((size_t)(b * 512 + (n0 - 1024) + c)) * 1024 + nn0 + half * 32;
#pragma unroll
            for (int j = 0; j < 4; ++j) {
                const int s = half * 4 + j;
                h8 v = *(const h8*)&lC[c * 64 + ((s ^ (c & 7)) << 3)];
                *(h8*)&gdst[j * 8] = v;
            }
        } else {
#pragma unroll
            for (int mi = 0; mi < 2; ++mi)
#pragma unroll
                for (int ni = 0; ni < NI; ++ni)
#pragma unroll
                    for (int r = 0; r < 4; ++r) {
                        int row = m0 + wr * 32 + mi * 16 + hseg * 4 + r;
                        int col = n0 + wc * WN + ni * 16 + r16;
                        float v = acc[mi][ni][r];
                        int cc = col & 511;
                        int h = cc >> 6, d = cc & 63;
                        int b = row >> 10, nn = row & 1023;
                        if (col < 512)
                            qp[((b * 8 + h) * 1024 + nn) * 64 + d] = (_Float16)(v * QSCALE2);
                        else
                            kp[((b * 8 + h) * 1024 + nn) * 64 + d] = (_Float16)v;
                    }
        }
    } else {
#pragma unroll
        for (int mi = 0; mi < 2; ++mi)
#pragma unroll
            for (int ni = 0; ni < NI; ++ni)
#pragma unroll
                for (int r = 0; r < 4; ++r) {
                    int row = m0 + wr * 32 + mi * 16 + hseg * 4 + r;
                    int col = n0 + wc * WN + ni * 16 + r16;
                    float v = acc[mi][ni][r] + bias[col];
                    v = v > 0.f ? v : 0.f;
                    outh[(size_t)row * Ng + col] = (_Float16)v;
                }
    }
}

// ---------------- GEMM64: BM=128 x BN=64, 512 threads / 8 waves ----------------
// For the N=512 GEMMs (Wo, FFN2). Wave grid 4(m) x 2(n), wave tile 32x32 (same
// per-wave MFMA:ds_read ratio as the verified config). LDS 48 KB -> 3 blocks/CU
// x 8 waves = 24 waves/CU (vs 16 before). Grid = 64 M-tiles x 8 N-tiles = 512.
// EPI: outh = f16(acc + bias[col] + resh_f16[row][col])
__global__ void __launch_bounds__(512) k_gemm64(
    const _Float16* __restrict__ A, const _Float16* __restrict__ Bt,
    int Ng, int Kg,
    const float* __restrict__ bias,
    const _Float16* __restrict__ resh, _Float16* __restrict__ outh) {
    __shared__ alignas(16) _Float16 lA[2][128 * 64];
    __shared__ alignas(16) _Float16 lB[2][64 * 64];

    const int tid = threadIdx.x;
    const int lane = tid & 63;
    const int wid = tid >> 6;        // 0..7
    const int wr = wid >> 1;         // 0..3 -> 32-row stripe of 128
    const int wc = wid & 1;          // 0..1 -> 32-col stripe of 64
    const int r16 = lane & 15, hseg = lane >> 4;

    // XCD-aware tile decode (M tiles = 64: 8 per XCD)
    const int bid = blockIdx.x;
    const int xcd = bid & 7;
    const int rem = bid >> 3;
    const int tx = rem >> 3, tyl = rem & 7;
    const int m0 = (xcd * 8 + tyl) * 128;
    const int n0 = tx * 64;

    auto STAGE = [&](int buf, int k0) {
#pragma unroll
        for (int i = 0; i < 2; ++i) {    // A: 128 rows x 8 slots = 1024 slots
            const int slot = i * 512 + tid, row = slot >> 3;
            const int cs = (slot & 7) ^ (row & 7);
            GLOAD_LDS16(A + (size_t)(m0 + row) * Kg + k0 + cs * 8, &lA[buf][slot * 8]);
        }
        {                                 // B: 64 rows x 8 slots = 512 slots
            const int slot = tid, row = slot >> 3;
            const int cs = (slot & 7) ^ (row & 7);
            GLOAD_LDS16(Bt + (size_t)(n0 + row) * Kg + k0 + cs * 8, &lB[buf][slot * 8]);
        }
    };

    f32x4 acc[2][2] = {};
    const int nt = Kg >> 6;

    STAGE(0, 0);
    __syncthreads();

    for (int t = 0; t < nt; ++t) {
        const int cur = t & 1;
        if (t + 1 < nt) STAGE(cur ^ 1, (t + 1) << 6);

#pragma unroll
        for (int kk = 0; kk < 2; ++kk) {
            h8 af[2], bf[2];
#pragma unroll
            for (int mi = 0; mi < 2; ++mi) {
                const int row = wr * 32 + mi * 16 + r16;
                af[mi] = *(const h8*)&lA[cur][row * 64 + (((kk * 4 + hseg) ^ (row & 7)) * 8)];
            }
#pragma unroll
            for (int ni = 0; ni < 2; ++ni) {
                const int row = wc * 32 + ni * 16 + r16;
                bf[ni] = *(const h8*)&lB[cur][row * 64 + (((kk * 4 + hseg) ^ (row & 7)) * 8)];
            }
#pragma unroll
            for (int mi = 0; mi < 2; ++mi)
#pragma unroll
                for (int ni = 0; ni < 2; ++ni)
                    acc[mi][ni] =
                        __builtin_amdgcn_mfma_f32_16x16x32_f16(af[mi], bf[ni], acc[mi][ni], 0, 0, 0);
        }
        __syncthreads();
    }

    // epilogue: row = m0 + wr*32 + mi*16 + hseg*4 + r; col = n0 + wc*32 + ni*16 + r16
#pragma unroll
    for (int mi = 0; mi < 2; ++mi)
#pragma unroll
        for (int ni = 0; ni < 2; ++ni)
#pragma unroll
            for (int r = 0; r < 4; ++r) {
                int row = m0 + wr * 32 + mi * 16 + hseg * 4 + r;
                int col = n0 + wc * 32 + ni * 16 + r16;
                float v = acc[mi][ni][r] + bias[col] + (float)resh[(size_t)row * Ng + col];
                outh[(size_t)row * Ng + col] = (_Float16)v;
            }
}

// ---------------- flash attention: 1 block = (b,h) x 128 q-rows, 8 waves --------
// R12-verified: swapped QK^T, XOR-swizzle, per-lane partial softmax sum,
// rare defer-max rescale, 2-phase prefetch, setprio on MFMA clusters.
__global__ void __launch_bounds__(512) k_attn(const _Float16* __restrict__ q,
                                              const _Float16* __restrict__ k,
                                              const _Float16* __restrict__ vt,
                                              _Float16* __restrict__ attn) {
    __shared__ alignas(16) _Float16 lK[2][64 * 64];   // [key][d], swizzled
    __shared__ alignas(16) _Float16 lV[2][64 * 64];   // [d][key], swizzled
    __shared__ alignas(16) _Float16 lP[8][16 * 64];   // per-wave P tile, swizzled

    const int tid = threadIdx.x, lane = tid & 63, w = tid >> 6;
    const int bid = blockIdx.x;                  // 512 blocks = 64 per XCD
    const int xcd = bid & 7, rem = bid >> 3;
    const int bh = xcd * 8 + (rem & 7);
    const int q0 = (rem >> 3) * 128;
    const int r16 = lane & 15, hseg = lane >> 4;
    const size_t base = (size_t)bh * N_ * D_;

    h8 qf0 = *(const h8*)&q[base + (size_t)(q0 + w * 16 + r16) * 64 + hseg * 8];
    h8 qf1 = *(const h8*)&q[base + (size_t)(q0 + w * 16 + r16) * 64 + 32 + hseg * 8];

    const int srow = tid >> 3;
    const int scsrc = (tid & 7) ^ (srow & 7);

    auto STAGE = [&](int buf, int kt) {
        GLOAD_LDS16(k + base + kt * 4096 + srow * 64 + scsrc * 8, &lK[buf][tid * 8]);
        GLOAD_LDS16(vt + base + (size_t)srow * N_ + kt * 64 + scsrc * 8, &lV[buf][tid * 8]);
    };

    float mrun = -1e30f, lrun = 0.f;
    f32x4 oacc[4] = {};  // O[q = hseg*4+r][d = nf*16+r16]

    const char* lKb = (const char*)&lK[0][0];
    const char* lVb = (const char*)&lV[0][0];
    char* lPb = (char*)&lP[0][0] + w * 2048;
    const int swz = r16 & 7;
    const int kb0 = r16 * 128 + ((hseg ^ swz) * 16);        // kc=0 (lK & lV share)
    const int kb1 = r16 * 128 + (((4 + hseg) ^ swz) * 16);  // kc=1
    const int pswz = swz * 8;
    const int prd0 = r16 * 128 + (((hseg * 8) ^ pswz) * 2);
    const int prd1 = r16 * 128 + (((32 + hseg * 8) ^ pswz) * 2);
    const int pwr0 = r16 * 128 + (((0 + hseg * 4) ^ pswz) * 2);
    const int pwr1 = r16 * 128 + (((16 + hseg * 4) ^ pswz) * 2);
    const int pwr2 = r16 * 128 + (((32 + hseg * 4) ^ pswz) * 2);
    const int pwr3 = r16 * 128 + (((48 + hseg * 4) ^ pswz) * 2);

    auto TILE = [&](const int cur, const int kt) __attribute__((always_inline)) {
        if (kt + 1 < N_ / 64) STAGE(cur ^ 1, kt + 1);  // prefetch overlaps compute
        const int cOff = cur * 8192;  // one buffer = 64*64*2 bytes

        float sv[4][4];
        __builtin_amdgcn_s_setprio(1);
#pragma unroll
        for (int t4 = 0; t4 < 4; ++t4) {
            f32x4 a = {};
            h8 kf0 = *(const h8*)(lKb + cOff + t4 * 2048 + kb0);
            a = __builtin_amdgcn_mfma_f32_16x16x32_f16(kf0, qf0, a, 0, 0, 0);
            h8 kf1 = *(const h8*)(lKb + cOff + t4 * 2048 + kb1);
            a = __builtin_amdgcn_mfma_f32_16x16x32_f16(kf1, qf1, a, 0, 0, 0);
#pragma unroll
            for (int r = 0; r < 4; ++r) sv[t4][r] = a[r];
        }
        __builtin_amdgcn_s_setprio(0);

        float m0a = fmaxf(fmaxf(sv[0][0], sv[0][1]), fmaxf(sv[0][2], sv[0][3]));
        float m1a = fmaxf(fmaxf(sv[1][0], sv[1][1]), fmaxf(sv[1][2], sv[1][3]));
        float m2a = fmaxf(fmaxf(sv[2][0], sv[2][1]), fmaxf(sv[2][2], sv[2][3]));
        float m3a = fmaxf(fmaxf(sv[3][0], sv[3][1]), fmaxf(sv[3][2], sv[3][3]));
        float mx = fmaxf(fmaxf(m0a, m1a), fmaxf(m2a, m3a));

        if (__any(mx > mrun + 8.f)) {
            mx = fmaxf(mx, __shfl_xor(mx, 16));
            mx = fmaxf(mx, __shfl_xor(mx, 32));
            float mnew = fmaxf(mrun, mx);
            float sc = exp2_raw(mrun - mnew);
            mrun = mnew;
            lrun *= sc;
#pragma unroll
            for (int r = 0; r < 4; ++r) {
                float scq = __shfl(sc, hseg * 4 + r);
#pragma unroll
                for (int nf = 0; nf < 4; ++nf) oacc[nf][r] *= scq;
            }
        }

        float p[4][4];
        float rsum = 0.f;
#pragma unroll
        for (int t4 = 0; t4 < 4; ++t4)
#pragma unroll
            for (int r = 0; r < 4; ++r) {
                p[t4][r] = exp2_raw(sv[t4][r] - mrun);
                rsum += p[t4][r];
            }
        lrun += rsum;

#pragma unroll
        for (int t4 = 0; t4 < 4; ++t4) {
            g2 a0 = __builtin_amdgcn_cvt_pkrtz(p[t4][0], p[t4][1]);
            g2 a1 = __builtin_amdgcn_cvt_pkrtz(p[t4][2], p[t4][3]);
            h4 pv = {(_Float16)a0[0], (_Float16)a0[1], (_Float16)a1[0], (_Float16)a1[1]};
            char* dst = lPb + (t4 == 0 ? pwr0 : t4 == 1 ? pwr1 : t4 == 2 ? pwr2 : pwr3);
            *(h4*)dst = pv;
        }
        asm volatile("s_waitcnt lgkmcnt(0)" ::: "memory");  // wave-internal LDS fence

        h8 pa0 = *(const h8*)(lPb + prd0);
        h8 pa1 = *(const h8*)(lPb + prd1);
        __builtin_amdgcn_s_setprio(1);
#pragma unroll
        for (int nf = 0; nf < 4; ++nf) {
            h8 vb0 = *(const h8*)(lVb + cOff + nf * 2048 + kb0);
            oacc[nf] = __builtin_amdgcn_mfma_f32_16x16x32_f16(pa0, vb0, oacc[nf], 0, 0, 0);
            h8 vb1 = *(const h8*)(lVb + cOff + nf * 2048 + kb1);
            oacc[nf] = __builtin_amdgcn_mfma_f32_16x16x32_f16(pa1, vb1, oacc[nf], 0, 0, 0);
        }
        __builtin_amdgcn_s_setprio(0);
        __syncthreads();  // drains prefetch vmcnt + guards buffer swap
    };

    STAGE(0, 0);
    __syncthreads();  // drains vmcnt: buf0 ready

    for (int kt = 0; kt < N_ / 64; kt += 2) {
        TILE(0, kt);
        TILE(1, kt + 1);
    }

    lrun += __shfl_xor(lrun, 16);
    lrun += __shfl_xor(lrun, 32);

    float rlin = 1.f / lrun;
    int b = bh >> 3, h = bh & 7;
#pragma unroll
    for (int r = 0; r < 4; ++r) {
        float inv = __shfl(rlin, hseg * 4 + r);
        int row = b * 1024 + q0 + w * 16 + hseg * 4 + r;
#pragma unroll
        for (int nf = 0; nf < 4; ++nf) {
            int col = h * 64 + nf * 16 + r16;
            attn[(size_t)row * 512 + col] = (_Float16)(oacc[nf][r] * inv);
        }
    }
}

// ---------------- layernorm: 1 wave per row of 512, f16 in ----------------
// OUTF32=1: write f32 (+tail); else write f16.
template <int OUTF32>
__global__ void __launch_bounds__(256) k_ln(const _Float16* __restrict__ x,
                                            const float* __restrict__ g,
                                            const float* __restrict__ b,
                                            float* __restrict__ outf,
                                            _Float16* __restrict__ outh,
                                            float* __restrict__ tail) {
    int row = blockIdx.x * 4 + (threadIdx.x >> 6);
    int lane = threadIdx.x & 63;
    h8 v = *(const h8*)(x + (size_t)row * 512 + lane * 8);
    float f[8];
    float s = 0.f, sq = 0.f;
#pragma unroll
    for (int j = 0; j < 8; ++j) {
        f[j] = (float)v[j];
        s += f[j];
        sq += f[j] * f[j];
    }
#pragma unroll
    for (int msk = 1; msk < 64; msk <<= 1) {
        s += __shfl_xor(s, msk);
        sq += __shfl_xor(sq, msk);
    }
    float mu = s * (1.f / 512.f);
    float var = sq * (1.f / 512.f) - mu * mu;
    float rstd = rsqrtf(var + 1e-5f);
    float4 ga = *(const float4*)(g + lane * 8);
    float4 gb = *(const float4*)(g + lane * 8 + 4);
    float4 ba = *(const float4*)(b + lane * 8);
    float4 bb = *(const float4*)(b + lane * 8 + 4);
    float o[8];
    o[0] = (f[0] - mu) * rstd * ga.x + ba.x;
    o[1] = (f[1] - mu) * rstd * ga.y + ba.y;
    o[2] = (f[2] - mu) * rstd * ga.z + ba.z;
    o[3] = (f[3] - mu) * rstd * ga.w + ba.w;
    o[4] = (f[4] - mu) * rstd * gb.x + bb.x;
    o[5] = (f[5] - mu) * rstd * gb.y + bb.y;
    o[6] = (f[6] - mu) * rstd * gb.z + bb.z;
    o[7] = (f[7] - mu) * rstd * gb.w + bb.w;
    if constexpr (OUTF32) {
        float* orow = outf + (size_t)row * 512 + lane * 8;
        *(float4*)(orow) = make_float4(o[0], o[1], o[2], o[3]);
        *(float4*)(orow + 4) = make_float4(o[4], o[5], o[6], o[7]);
        if (tail && blockIdx.x == 0 && threadIdx.x == 0) tail[0] = 0.f;
    } else {
        h8 oh = {(_Float16)o[0], (_Float16)o[1], (_Float16)o[2], (_Float16)o[3],
                 (_Float16)o[4], (_Float16)o[5], (_Float16)o[6], (_Float16)o[7]};
        *(h8*)(outh + (size_t)row * 512 + lane * 8) = oh;
    }
}

// ---------------- launch ----------------
extern "C" void kernel_launch(void* const* d_in, const int* in_sizes, int n_in,
                              void* d_out, int out_size, void* d_ws, size_t ws_size,
                              hipStream_t stream) {
    const float* x   = (const float*)d_in[0];
    const float* Wq  = (const float*)d_in[1];
    const float* Wk  = (const float*)d_in[2];
    const float* Wv  = (const float*)d_in[3];
    const float* Wo  = (const float*)d_in[4];
    const float* bo  = (const float*)d_in[5];
    const float* g1  = (const float*)d_in[6];
    const float* b1  = (const float*)d_in[7];
    const float* W1  = (const float*)d_in[8];
    const float* bf1 = (const float*)d_in[9];
    const float* W2  = (const float*)d_in[10];
    const float* bf2 = (const float*)d_in[11];
    const float* g2  = (const float*)d_in[12];
    const float* b2  = (const float*)d_in[13];
    float* out = (float*)d_out;

    char* ws = (char*)d_ws;
    _Float16* xh    = (_Float16*)(ws + 0);            // 8 MB; reused as out1h after Wo
    _Float16* wqkvT = (_Float16*)(ws + 8388608);      // 1.5 MB  [1536][512]
    _Float16* woT   = (_Float16*)(ws + 9961472);      // 0.5 MB
    _Float16* w1T   = (_Float16*)(ws + 10485760);     // 2 MB    [2048][512]
    _Float16* w2T   = (_Float16*)(ws + 12582912);     // 2 MB    [512][2048]
    _Float16* qb    = (_Float16*)(ws + 14680064);     // 8 MB; ff (32 MB) reuses qb..attnb
    _Float16* kb    = (_Float16*)(ws + 23068672);     // 8 MB
    _Float16* vtb   = (_Float16*)(ws + 31457280);     // 8 MB
    _Float16* attnb = (_Float16*)(ws + 39845888);     // 8 MB
    _Float16* h1h   = (_Float16*)(ws + 48234496);     // 8 MB f16 (h1, reused as h2)
    _Float16* out1h = xh;
    _Float16* ff    = qb;

    // stage 0: fused dtype conversion + weight transposes
    k_pre<<<dim3(1024, 1, 13), 256, 0, stream>>>(x, xh, Wq, Wk, Wv, Wo, W1, W2,
                                                 wqkvT, woT, w1T, w2T);

    // QKV projection (fused, N=1536): BM=64/BN=128 -> grid 12*128 = 1536
    k_gemm<0><<<dim3(1536), 256, 0, stream>>>(
        xh, wqkvT, M_, 1536, 512, nullptr, nullptr, qb, kb, vtb);

    // attention: 512 blocks x 8 waves, XCD-decoded
    k_attn<<<dim3(512), 512, 0, stream>>>(qb, kb, vtb, attnb);

    // Wo projection + bias + residual(xh, f16) -> h1h: BM=128/BN=64, 8 waves, grid 512
    k_gemm64<<<dim3(512), 512, 0, stream>>>(attnb, woT, 512, 512, bo, xh, h1h);

    // LN1 -> out1h (f16; overwrites xh AFTER Wo consumed it)
    k_ln<0><<<dim3(M_ / 4), 256, 0, stream>>>(h1h, g1, b1, nullptr, out1h, nullptr);

    // FFN1: relu(out1 @ W1 + bf1) -> ff (f16): BM=64/BN=128 -> grid 2048
    k_gemm<2><<<dim3(2048), 256, 0, stream>>>(
        out1h, w1T, M_, 2048, 512, bf1, ff, nullptr, nullptr, nullptr);

    // FFN2: ff @ W2 + bf2 + out1 (f16 residual) -> h1h reused: BM=128/BN=64, grid 512
    k_gemm64<<<dim3(512), 512, 0, stream>>>(ff, w2T, 512, 2048, bf2, out1h, h1h);

    // LN2 -> d_out (fp32) + trailing scalar (reference returns (out3, 0))
    k_ln<1><<<dim3(M_ / 4), 256, 0, stream>>>(h1h, g2, b2, out, nullptr, out + (size_t)M_ * E_);
}

// Round 16
// 138.931 us; speedup vs baseline: 1.2017x; 1.0407x over previous
//
#include <hip/hip_runtime.h>
#include <cstdint>
#include <cstddef>

// ---------------- types ----------------
typedef _Float16 h8 __attribute__((ext_vector_type(8)));
typedef _Float16 h4 __attribute__((ext_vector_type(4)));
typedef __fp16   g2 __attribute__((ext_vector_type(2)));   // cvt_pkrtz result type
typedef float    f32x4 __attribute__((ext_vector_type(4)));

constexpr int B_ = 8, N_ = 1024, E_ = 512, H_ = 8, D_ = 64, F_ = 2048;
constexpr int M_ = B_ * N_;   // 8192 rows
constexpr int HD_ = H_ * D_;  // 512

// q pre-scale: 1/sqrt(D) * log2(e)  (softmax done in base 2)
#define QSCALE2 0.18033688011112042f

#define GLOAD_LDS16(gp, lp)                                                        \
    __builtin_amdgcn_global_load_lds((const __attribute__((address_space(1))) void*)(gp), \
                                     (__attribute__((address_space(3))) void*)(lp), 16, 0, 0)

// raw hardware exp2 (no libm denormal guard; underflow -> 0 is fine for softmax)
__device__ __forceinline__ float exp2_raw(float x) {
#if __has_builtin(__builtin_amdgcn_exp2f)
    return __builtin_amdgcn_exp2f(x);
#else
    float r;
    asm("v_exp_f32 %0, %1\n\ts_nop 0" : "=v"(r) : "v"(x));
    return r;
#endif
}

// ---------------- fused prep: weight transposes (z<12) + x f32->f16 (z==12) ----
__global__ void __launch_bounds__(256) k_pre(
    const float* __restrict__ x, _Float16* __restrict__ xh,
    const float* __restrict__ Wq, const float* __restrict__ Wk,
    const float* __restrict__ Wv, const float* __restrict__ Wo,
    const float* __restrict__ W1, const float* __restrict__ W2,
    _Float16* __restrict__ oqkv, _Float16* __restrict__ oo,
    _Float16* __restrict__ o1, _Float16* __restrict__ o2) {
    if (blockIdx.z == 12) {
        int i = (blockIdx.x * 256 + threadIdx.x) * 16;
#pragma unroll
        for (int j = 0; j < 4; ++j) {
            float4 v = *(const float4*)(x + i + j * 4);
            h4 o = {(_Float16)v.x, (_Float16)v.y, (_Float16)v.z, (_Float16)v.w};
            *(h4*)(xh + i + j * 4) = o;
        }
        return;
    }
    if (blockIdx.x >= 256) return;
    const float* in;
    _Float16* out;
    int R, C, gt = blockIdx.x;
    switch (blockIdx.z) {
        case 0: in = Wq; out = oqkv;              R = 512;  C = 512;  break;
        case 1: in = Wk; out = oqkv + 512 * 512;  R = 512;  C = 512;  break;
        case 2: in = Wv; out = oqkv + 1024 * 512; R = 512;  C = 512;  break;
        case 3: in = Wo; out = oo;                R = 512;  C = 512;  break;
        default:
            if (blockIdx.z < 8) { in = W1; out = o1; R = 512;  C = 2048; gt += (blockIdx.z - 4) * 256; }
            else                { in = W2; out = o2; R = 2048; C = 512;  gt += (blockIdx.z - 8) * 256; }
    }
    const int ctiles = C >> 5;
    const int ty = gt / ctiles, tx = gt - ty * ctiles;
    const int r0 = ty * 32, c0 = tx * 32;
    __shared__ float lt[32][33];
    const int rr = threadIdx.x >> 3, cq = threadIdx.x & 7;
    float4 v = *(const float4*)&in[(size_t)(r0 + rr) * C + c0 + cq * 4];
    lt[rr][cq * 4 + 0] = v.x; lt[rr][cq * 4 + 1] = v.y;
    lt[rr][cq * 4 + 2] = v.z; lt[rr][cq * 4 + 3] = v.w;
    __syncthreads();
    h4 o = {(_Float16)lt[cq * 4 + 0][rr], (_Float16)lt[cq * 4 + 1][rr],
            (_Float16)lt[cq * 4 + 2][rr], (_Float16)lt[cq * 4 + 3][rr]};
    *(h4*)&out[(size_t)(c0 + rr) * R + r0 + cq * 4] = o;
}

// ---------------- GEMM: BM=64 x BN=128, 256 threads, K=512 (nt=8) --------------
// T1 XCD decode, T2 XOR-swizzle, T4 counted-vmcnt 3-buffer pipeline, FULLY
// UNROLLED (all buffer indices literal; no sched_barrier — "memory" clobber
// orders the LDS/VMEM ops, data deps order the MFMAs). Per step: wait vmcnt(6)
// (retires tile t; tile t+1 stays in flight), s_barrier, stage tile t+2 into
// the buffer all waves finished reading before the PREVIOUS barrier, compute.
// EPI 0: QKV scatter (q *= QSCALE2, k direct, v transposed via LDS)
// EPI 2: outh = relu(acc + bias[col])  (f16)
template <int EPI>
__global__ void __launch_bounds__(256) k_gemm(
    const _Float16* __restrict__ A, const _Float16* __restrict__ Bt,
    int Mg, int Ng, int Kg,
    const float* __restrict__ bias,
    _Float16* __restrict__ outh,
    _Float16* __restrict__ qp, _Float16* __restrict__ kp, _Float16* __restrict__ vtp) {
    constexpr int BN = 128;
    constexpr int WN = BN / 2;       // wave tile cols
    constexpr int NI = WN / 16;      // n-frags per wave
    constexpr int NT = 8;            // K=512 / 64
    __shared__ alignas(16) _Float16 lA[3][64 * 64];    // 24 KB
    __shared__ alignas(16) _Float16 lB[3][BN * 64];    // 48 KB

    const int tid = threadIdx.x;
    const int lane = tid & 63;
    const int wid = tid >> 6;
    const int wr = wid >> 1, wc = wid & 1;
    const int r16 = lane & 15, hseg = lane >> 4;

    // XCD-aware tile decode (M tiles = 128: 16 per XCD)
    const int bid = blockIdx.x;
    const int xcd = bid & 7;
    const int rem = bid >> 3;
    const int tx = rem >> 4, tyl = rem & 15;
    const int m0 = (xcd * 16 + tyl) * 64;
    const int n0 = tx * BN;

    auto STAGE = [&](int buf, int k0) {
#pragma unroll
        for (int i = 0; i < 2; ++i) {
            const int slot = i * 256 + tid, row = slot >> 3;
            const int cs = (slot & 7) ^ (row & 7);
            GLOAD_LDS16(A + (size_t)(m0 + row) * Kg + k0 + cs * 8, &lA[buf][slot * 8]);
        }
#pragma unroll
        for (int i = 0; i < BN / 32; ++i) {
            const int slot = i * 256 + tid, row = slot >> 3;
            const int cs = (slot & 7) ^ (row & 7);
            GLOAD_LDS16(Bt + (size_t)(n0 + row) * Kg + k0 + cs * 8, &lB[buf][slot * 8]);
        }
    };

    f32x4 acc[2][NI] = {};

    auto COMPUTE = [&](const int buf) __attribute__((always_inline)) {
#pragma unroll
        for (int kk = 0; kk < 2; ++kk) {
            h8 af[2], bf[NI];
#pragma unroll
            for (int mi = 0; mi < 2; ++mi) {
                const int row = wr * 32 + mi * 16 + r16;
                af[mi] = *(const h8*)&lA[buf][row * 64 + (((kk * 4 + hseg) ^ (row & 7)) * 8)];
            }
#pragma unroll
            for (int ni = 0; ni < NI; ++ni) {
                const int row = wc * WN + ni * 16 + r16;
                bf[ni] = *(const h8*)&lB[buf][row * 64 + (((kk * 4 + hseg) ^ (row & 7)) * 8)];
            }
#pragma unroll
            for (int mi = 0; mi < 2; ++mi)
#pragma unroll
                for (int ni = 0; ni < NI; ++ni)
                    acc[mi][ni] =
                        __builtin_amdgcn_mfma_f32_16x16x32_f16(af[mi], bf[ni], acc[mi][ni], 0, 0, 0);
        }
    };

    STAGE(0, 0);
    STAGE(1, 64);
#pragma unroll
    for (int t = 0; t < NT; ++t) {
        if (t < NT - 1) asm volatile("s_waitcnt vmcnt(6)" ::: "memory");
        else            asm volatile("s_waitcnt vmcnt(0)" ::: "memory");
        __builtin_amdgcn_s_barrier();
        if (t + 2 < NT) STAGE((t + 2) % 3, (t + 2) * 64);
        COMPUTE(t % 3);
    }

    // epilogue: lane holds C[row = m0+wr*32+mi*16+hseg*4+r][col = n0+wc*WN+ni*16+r16]
    if constexpr (EPI == 0) {
        if (n0 >= 1024) {
            __syncthreads();  // all waves done reading lA before scratch reuse
            // V block: transpose 64xBN C-tile through LDS, coalesced h8 stores.
            _Float16* lC = &lA[0][0];
#pragma unroll
            for (int mi = 0; mi < 2; ++mi) {
                const int r0 = wr * 32 + mi * 16 + hseg * 4;
                const int s = r0 >> 3, ro = r0 & 7;
#pragma unroll
                for (int ni = 0; ni < NI; ++ni) {
                    const int c = wc * WN + ni * 16 + r16;
                    h4 pv = {(_Float16)acc[mi][ni][0], (_Float16)acc[mi][ni][1],
                             (_Float16)acc[mi][ni][2], (_Float16)acc[mi][ni][3]};
                    *(h4*)&lC[c * 64 + ((s ^ (c & 7)) << 3) + ro] = pv;
                }
            }
            __syncthreads();
            const int c = tid >> 1, half = tid & 1;
            const int b = m0 >> 10, nn0 = m0 & 1023;
            _Float16* gdst =
                vtp + ((size_t)(b * 512 + (n0 - 1024) + c)) * 1024 + nn0 + half * 32;
#pragma unroll
            for (int j = 0; j < 4; ++j) {
                const int s = half * 4 + j;
                h8 v = *(const h8*)&lC[c * 64 + ((s ^ (c & 7)) << 3)];
                *(h8*)&gdst[j * 8] = v;
            }
        } else {
#pragma unroll
            for (int mi = 0; mi < 2; ++mi)
#pragma unroll
                for (int ni = 0; ni < NI; ++ni)
#pragma unroll
                    for (int r = 0; r < 4; ++r) {
                        int row = m0 + wr * 32 + mi * 16 + hseg * 4 + r;
                        int col = n0 + wc * WN + ni * 16 + r16;
                        float v = acc[mi][ni][r];
                        int cc = col & 511;
                        int h = cc >> 6, d = cc & 63;
                        int b = row >> 10, nn = row & 1023;
                        if (col < 512)
                            qp[((b * 8 + h) * 1024 + nn) * 64 + d] = (_Float16)(v * QSCALE2);
                        else
                            kp[((b * 8 + h) * 1024 + nn) * 64 + d] = (_Float16)v;
                    }
        }
    } else {
#pragma unroll
        for (int mi = 0; mi < 2; ++mi)
#pragma unroll
            for (int ni = 0; ni < NI; ++ni)
#pragma unroll
                for (int r = 0; r < 4; ++r) {
                    int row = m0 + wr * 32 + mi * 16 + hseg * 4 + r;
                    int col = n0 + wc * WN + ni * 16 + r16;
                    float v = acc[mi][ni][r] + bias[col];
                    v = v > 0.f ? v : 0.f;
                    outh[(size_t)row * Ng + col] = (_Float16)v;
                }
    }
}

// ---------------- GEMM64: BM=128 x BN=64, 512 threads / 8 waves -----------------
// Same counted-vmcnt 3-buffer unrolled pipeline; loads/tile = 3 (A:2, B:1).
// NT templated: 8 (Wo, K=512) or 32 (FFN2, K=2048).
// EPI: outh = f16(acc + bias[col] + resh_f16[row][col])
template <int NT>
__global__ void __launch_bounds__(512) k_gemm64(
    const _Float16* __restrict__ A, const _Float16* __restrict__ Bt,
    int Ng, int Kg,
    const float* __restrict__ bias,
    const _Float16* __restrict__ resh, _Float16* __restrict__ outh) {
    __shared__ alignas(16) _Float16 lA[3][128 * 64];   // 48 KB
    __shared__ alignas(16) _Float16 lB[3][64 * 64];    // 24 KB

    const int tid = threadIdx.x;
    const int lane = tid & 63;
    const int wid = tid >> 6;        // 0..7
    const int wr = wid >> 1;         // 0..3 -> 32-row stripe of 128
    const int wc = wid & 1;          // 0..1 -> 32-col stripe of 64
    const int r16 = lane & 15, hseg = lane >> 4;

    // XCD-aware tile decode (M tiles = 64: 8 per XCD)
    const int bid = blockIdx.x;
    const int xcd = bid & 7;
    const int rem = bid >> 3;
    const int tx = rem >> 3, tyl = rem & 7;
    const int m0 = (xcd * 8 + tyl) * 128;
    const int n0 = tx * 64;

    auto STAGE = [&](int buf, int k0) {
#pragma unroll
        for (int i = 0; i < 2; ++i) {    // A: 128 rows x 8 slots = 1024 slots
            const int slot = i * 512 + tid, row = slot >> 3;
            const int cs = (slot & 7) ^ (row & 7);
            GLOAD_LDS16(A + (size_t)(m0 + row) * Kg + k0 + cs * 8, &lA[buf][slot * 8]);
        }
        {                                 // B: 64 rows x 8 slots = 512 slots
            const int slot = tid, row = slot >> 3;
            const int cs = (slot & 7) ^ (row & 7);
            GLOAD_LDS16(Bt + (size_t)(n0 + row) * Kg + k0 + cs * 8, &lB[buf][slot * 8]);
        }
    };

    f32x4 acc[2][2] = {};

    auto COMPUTE = [&](const int buf) __attribute__((always_inline)) {
#pragma unroll
        for (int kk = 0; kk < 2; ++kk) {
            h8 af[2], bf[2];
#pragma unroll
            for (int mi = 0; mi < 2; ++mi) {
                const int row = wr * 32 + mi * 16 + r16;
                af[mi] = *(const h8*)&lA[buf][row * 64 + (((kk * 4 + hseg) ^ (row & 7)) * 8)];
            }
#pragma unroll
            for (int ni = 0; ni < 2; ++ni) {
                const int row = wc * 32 + ni * 16 + r16;
                bf[ni] = *(const h8*)&lB[buf][row * 64 + (((kk * 4 + hseg) ^ (row & 7)) * 8)];
            }
#pragma unroll
            for (int mi = 0; mi < 2; ++mi)
#pragma unroll
                for (int ni = 0; ni < 2; ++ni)
                    acc[mi][ni] =
                        __builtin_amdgcn_mfma_f32_16x16x32_f16(af[mi], bf[ni], acc[mi][ni], 0, 0, 0);
        }
    };

    STAGE(0, 0);
    STAGE(1, 64);
#pragma unroll
    for (int t = 0; t < NT; ++t) {
        if (t < NT - 1) asm volatile("s_waitcnt vmcnt(3)" ::: "memory");
        else            asm volatile("s_waitcnt vmcnt(0)" ::: "memory");
        __builtin_amdgcn_s_barrier();
        if (t + 2 < NT) STAGE((t + 2) % 3, (t + 2) * 64);
        COMPUTE(t % 3);
    }

    // epilogue: row = m0 + wr*32 + mi*16 + hseg*4 + r; col = n0 + wc*32 + ni*16 + r16
#pragma unroll
    for (int mi = 0; mi < 2; ++mi)
#pragma unroll
        for (int ni = 0; ni < 2; ++ni)
#pragma unroll
            for (int r = 0; r < 4; ++r) {
                int row = m0 + wr * 32 + mi * 16 + hseg * 4 + r;
                int col = n0 + wc * 32 + ni * 16 + r16;
                float v = acc[mi][ni][r] + bias[col] + (float)resh[(size_t)row * Ng + col];
                outh[(size_t)row * Ng + col] = (_Float16)v;
            }
}

// ---------------- flash attention: 1 block = (b,h) x 128 q-rows, 8 waves --------
// R12-verified: swapped QK^T, XOR-swizzle, per-lane partial softmax sum,
// rare defer-max rescale, 2-phase prefetch, setprio on MFMA clusters.
__global__ void __launch_bounds__(512) k_attn(const _Float16* __restrict__ q,
                                              const _Float16* __restrict__ k,
                                              const _Float16* __restrict__ vt,
                                              _Float16* __restrict__ attn) {
    __shared__ alignas(16) _Float16 lK[2][64 * 64];   // [key][d], swizzled
    __shared__ alignas(16) _Float16 lV[2][64 * 64];   // [d][key], swizzled
    __shared__ alignas(16) _Float16 lP[8][16 * 64];   // per-wave P tile, swizzled

    const int tid = threadIdx.x, lane = tid & 63, w = tid >> 6;
    const int bid = blockIdx.x;                  // 512 blocks = 64 per XCD
    const int xcd = bid & 7, rem = bid >> 3;
    const int bh = xcd * 8 + (rem & 7);
    const int q0 = (rem >> 3) * 128;
    const int r16 = lane & 15, hseg = lane >> 4;
    const size_t base = (size_t)bh * N_ * D_;

    h8 qf0 = *(const h8*)&q[base + (size_t)(q0 + w * 16 + r16) * 64 + hseg * 8];
    h8 qf1 = *(const h8*)&q[base + (size_t)(q0 + w * 16 + r16) * 64 + 32 + hseg * 8];

    const int srow = tid >> 3;
    const int scsrc = (tid & 7) ^ (srow & 7);

    auto STAGE = [&](int buf, int kt) {
        GLOAD_LDS16(k + base + kt * 4096 + srow * 64 + scsrc * 8, &lK[buf][tid * 8]);
        GLOAD_LDS16(vt + base + (size_t)srow * N_ + kt * 64 + scsrc * 8, &lV[buf][tid * 8]);
    };

    float mrun = -1e30f, lrun = 0.f;
    f32x4 oacc[4] = {};  // O[q = hseg*4+r][d = nf*16+r16]

    const char* lKb = (const char*)&lK[0][0];
    const char* lVb = (const char*)&lV[0][0];
    char* lPb = (char*)&lP[0][0] + w * 2048;
    const int swz = r16 & 7;
    const int kb0 = r16 * 128 + ((hseg ^ swz) * 16);        // kc=0 (lK & lV share)
    const int kb1 = r16 * 128 + (((4 + hseg) ^ swz) * 16);  // kc=1
    const int pswz = swz * 8;
    const int prd0 = r16 * 128 + (((hseg * 8) ^ pswz) * 2);
    const int prd1 = r16 * 128 + (((32 + hseg * 8) ^ pswz) * 2);
    const int pwr0 = r16 * 128 + (((0 + hseg * 4) ^ pswz) * 2);
    const int pwr1 = r16 * 128 + (((16 + hseg * 4) ^ pswz) * 2);
    const int pwr2 = r16 * 128 + (((32 + hseg * 4) ^ pswz) * 2);
    const int pwr3 = r16 * 128 + (((48 + hseg * 4) ^ pswz) * 2);

    auto TILE = [&](const int cur, const int kt) __attribute__((always_inline)) {
        if (kt + 1 < N_ / 64) STAGE(cur ^ 1, kt + 1);  // prefetch overlaps compute
        const int cOff = cur * 8192;  // one buffer = 64*64*2 bytes

        float sv[4][4];
        __builtin_amdgcn_s_setprio(1);
#pragma unroll
        for (int t4 = 0; t4 < 4; ++t4) {
            f32x4 a = {};
            h8 kf0 = *(const h8*)(lKb + cOff + t4 * 2048 + kb0);
            a = __builtin_amdgcn_mfma_f32_16x16x32_f16(kf0, qf0, a, 0, 0, 0);
            h8 kf1 = *(const h8*)(lKb + cOff + t4 * 2048 + kb1);
            a = __builtin_amdgcn_mfma_f32_16x16x32_f16(kf1, qf1, a, 0, 0, 0);
#pragma unroll
            for (int r = 0; r < 4; ++r) sv[t4][r] = a[r];
        }
        __builtin_amdgcn_s_setprio(0);

        float m0a = fmaxf(fmaxf(sv[0][0], sv[0][1]), fmaxf(sv[0][2], sv[0][3]));
        float m1a = fmaxf(fmaxf(sv[1][0], sv[1][1]), fmaxf(sv[1][2], sv[1][3]));
        float m2a = fmaxf(fmaxf(sv[2][0], sv[2][1]), fmaxf(sv[2][2], sv[2][3]));
        float m3a = fmaxf(fmaxf(sv[3][0], sv[3][1]), fmaxf(sv[3][2], sv[3][3]));
        float mx = fmaxf(fmaxf(m0a, m1a), fmaxf(m2a, m3a));

        if (__any(mx > mrun + 8.f)) {
            mx = fmaxf(mx, __shfl_xor(mx, 16));
            mx = fmaxf(mx, __shfl_xor(mx, 32));
            float mnew = fmaxf(mrun, mx);
            float sc = exp2_raw(mrun - mnew);
            mrun = mnew;
            lrun *= sc;
#pragma unroll
            for (int r = 0; r < 4; ++r) {
                float scq = __shfl(sc, hseg * 4 + r);
#pragma unroll
                for (int nf = 0; nf < 4; ++nf) oacc[nf][r] *= scq;
            }
        }

        float p[4][4];
        float rsum = 0.f;
#pragma unroll
        for (int t4 = 0; t4 < 4; ++t4)
#pragma unroll
            for (int r = 0; r < 4; ++r) {
                p[t4][r] = exp2_raw(sv[t4][r] - mrun);
                rsum += p[t4][r];
            }
        lrun += rsum;

#pragma unroll
        for (int t4 = 0; t4 < 4; ++t4) {
            g2 a0 = __builtin_amdgcn_cvt_pkrtz(p[t4][0], p[t4][1]);
            g2 a1 = __builtin_amdgcn_cvt_pkrtz(p[t4][2], p[t4][3]);
            h4 pv = {(_Float16)a0[0], (_Float16)a0[1], (_Float16)a1[0], (_Float16)a1[1]};
            char* dst = lPb + (t4 == 0 ? pwr0 : t4 == 1 ? pwr1 : t4 == 2 ? pwr2 : pwr3);
            *(h4*)dst = pv;
        }
        asm volatile("s_waitcnt lgkmcnt(0)" ::: "memory");  // wave-internal LDS fence

        h8 pa0 = *(const h8*)(lPb + prd0);
        h8 pa1 = *(const h8*)(lPb + prd1);
        __builtin_amdgcn_s_setprio(1);
#pragma unroll
        for (int nf = 0; nf < 4; ++nf) {
            h8 vb0 = *(const h8*)(lVb + cOff + nf * 2048 + kb0);
            oacc[nf] = __builtin_amdgcn_mfma_f32_16x16x32_f16(pa0, vb0, oacc[nf], 0, 0, 0);
            h8 vb1 = *(const h8*)(lVb + cOff + nf * 2048 + kb1);
            oacc[nf] = __builtin_amdgcn_mfma_f32_16x16x32_f16(pa1, vb1, oacc[nf], 0, 0, 0);
        }
        __builtin_amdgcn_s_setprio(0);
        __syncthreads();  // drains prefetch vmcnt + guards buffer swap
    };

    STAGE(0, 0);
    __syncthreads();  // drains vmcnt: buf0 ready

    for (int kt = 0; kt < N_ / 64; kt += 2) {
        TILE(0, kt);
        TILE(1, kt + 1);
    }

    lrun += __shfl_xor(lrun, 16);
    lrun += __shfl_xor(lrun, 32);

    float rlin = 1.f / lrun;
    int b = bh >> 3, h = bh & 7;
#pragma unroll
    for (int r = 0; r < 4; ++r) {
        float inv = __shfl(rlin, hseg * 4 + r);
        int row = b * 1024 + q0 + w * 16 + hseg * 4 + r;
#pragma unroll
        for (int nf = 0; nf < 4; ++nf) {
            int col = h * 64 + nf * 16 + r16;
            attn[(size_t)row * 512 + col] = (_Float16)(oacc[nf][r] * inv);
        }
    }
}

// ---------------- layernorm: 1 wave per row of 512, f16 in ----------------
// OUTF32=1: write f32 (+tail); else write f16.
template <int OUTF32>
__global__ void __launch_bounds__(256) k_ln(const _Float16* __restrict__ x,
                                            const float* __restrict__ g,
                                            const float* __restrict__ b,
                                            float* __restrict__ outf,
                                            _Float16* __restrict__ outh,
                                            float* __restrict__ tail) {
    int row = blockIdx.x * 4 + (threadIdx.x >> 6);
    int lane = threadIdx.x & 63;
    h8 v = *(const h8*)(x + (size_t)row * 512 + lane * 8);
    float f[8];
    float s = 0.f, sq = 0.f;
#pragma unroll
    for (int j = 0; j < 8; ++j) {
        f[j] = (float)v[j];
        s += f[j];
        sq += f[j] * f[j];
    }
#pragma unroll
    for (int msk = 1; msk < 64; msk <<= 1) {
        s += __shfl_xor(s, msk);
        sq += __shfl_xor(sq, msk);
    }
    float mu = s * (1.f / 512.f);
    float var = sq * (1.f / 512.f) - mu * mu;
    float rstd = rsqrtf(var + 1e-5f);
    float4 ga = *(const float4*)(g + lane * 8);
    float4 gb = *(const float4*)(g + lane * 8 + 4);
    float4 ba = *(const float4*)(b + lane * 8);
    float4 bb = *(const float4*)(b + lane * 8 + 4);
    float o[8];
    o[0] = (f[0] - mu) * rstd * ga.x + ba.x;
    o[1] = (f[1] - mu) * rstd * ga.y + ba.y;
    o[2] = (f[2] - mu) * rstd * ga.z + ba.z;
    o[3] = (f[3] - mu) * rstd * ga.w + ba.w;
    o[4] = (f[4] - mu) * rstd * gb.x + bb.x;
    o[5] = (f[5] - mu) * rstd * gb.y + bb.y;
    o[6] = (f[6] - mu) * rstd * gb.z + bb.z;
    o[7] = (f[7] - mu) * rstd * gb.w + bb.w;
    if constexpr (OUTF32) {
        float* orow = outf + (size_t)row * 512 + lane * 8;
        *(float4*)(orow) = make_float4(o[0], o[1], o[2], o[3]);
        *(float4*)(orow + 4) = make_float4(o[4], o[5], o[6], o[7]);
        if (tail && blockIdx.x == 0 && threadIdx.x == 0) tail[0] = 0.f;
    } else {
        h8 oh = {(_Float16)o[0], (_Float16)o[1], (_Float16)o[2], (_Float16)o[3],
                 (_Float16)o[4], (_Float16)o[5], (_Float16)o[6], (_Float16)o[7]};
        *(h8*)(outh + (size_t)row * 512 + lane * 8) = oh;
    }
}

// ---------------- launch ----------------
extern "C" void kernel_launch(void* const* d_in, const int* in_sizes, int n_in,
                              void* d_out, int out_size, void* d_ws, size_t ws_size,
                              hipStream_t stream) {
    const float* x   = (const float*)d_in[0];
    const float* Wq  = (const float*)d_in[1];
    const float* Wk  = (const float*)d_in[2];
    const float* Wv  = (const float*)d_in[3];
    const float* Wo  = (const float*)d_in[4];
    const float* bo  = (const float*)d_in[5];
    const float* g1  = (const float*)d_in[6];
    const float* b1  = (const float*)d_in[7];
    const float* W1  = (const float*)d_in[8];
    const float* bf1 = (const float*)d_in[9];
    const float* W2  = (const float*)d_in[10];
    const float* bf2 = (const float*)d_in[11];
    const float* g2  = (const float*)d_in[12];
    const float* b2  = (const float*)d_in[13];
    float* out = (float*)d_out;

    char* ws = (char*)d_ws;
    _Float16* xh    = (_Float16*)(ws + 0);            // 8 MB; reused as out1h after Wo
    _Float16* wqkvT = (_Float16*)(ws + 8388608);      // 1.5 MB  [1536][512]
    _Float16* woT   = (_Float16*)(ws + 9961472);      // 0.5 MB
    _Float16* w1T   = (_Float16*)(ws + 10485760);     // 2 MB    [2048][512]
    _Float16* w2T   = (_Float16*)(ws + 12582912);     // 2 MB    [512][2048]
    _Float16* qb    = (_Float16*)(ws + 14680064);     // 8 MB; ff (32 MB) reuses qb..attnb
    _Float16* kb    = (_Float16*)(ws + 23068672);     // 8 MB
    _Float16* vtb   = (_Float16*)(ws + 31457280);     // 8 MB
    _Float16* attnb = (_Float16*)(ws + 39845888);     // 8 MB
    _Float16* h1h   = (_Float16*)(ws + 48234496);     // 8 MB f16 (h1, reused as h2)
    _Float16* out1h = xh;
    _Float16* ff    = qb;

    // stage 0: fused dtype conversion + weight transposes
    k_pre<<<dim3(1024, 1, 13), 256, 0, stream>>>(x, xh, Wq, Wk, Wv, Wo, W1, W2,
                                                 wqkvT, woT, w1T, w2T);

    // QKV projection (fused, N=1536): BM=64/BN=128 -> grid 12*128 = 1536
    k_gemm<0><<<dim3(1536), 256, 0, stream>>>(
        xh, wqkvT, M_, 1536, 512, nullptr, nullptr, qb, kb, vtb);

    // attention: 512 blocks x 8 waves, XCD-decoded
    k_attn<<<dim3(512), 512, 0, stream>>>(qb, kb, vtb, attnb);

    // Wo projection + bias + residual(xh, f16) -> h1h: BM=128/BN=64, grid 512
    k_gemm64<8><<<dim3(512), 512, 0, stream>>>(attnb, woT, 512, 512, bo, xh, h1h);

    // LN1 -> out1h (f16; overwrites xh AFTER Wo consumed it)
    k_ln<0><<<dim3(M_ / 4), 256, 0, stream>>>(h1h, g1, b1, nullptr, out1h, nullptr);

    // FFN1: relu(out1 @ W1 + bf1) -> ff (f16): BM=64/BN=128 -> grid 2048
    k_gemm<2><<<dim3(2048), 256, 0, stream>>>(
        out1h, w1T, M_, 2048, 512, bf1, ff, nullptr, nullptr, nullptr);

    // FFN2: ff @ W2 + bf2 + out1 (f16 residual) -> h1h reused: BM=128/BN=64, grid 512
    k_gemm64<32><<<dim3(512), 512, 0, stream>>>(ff, w2T, 512, 2048, bf2, out1h, h1h);

    // LN2 -> d_out (fp32) + trailing scalar (reference returns (out3, 0))
    k_ln<1><<<dim3(M_ / 4), 256, 0, stream>>>(h1h, g2, b2, out, nullptr, out + (size_t)M_ * E_);
}